// Round 17
// baseline (124.832 us; speedup 1.0000x reference)
//
#include <hip/hip_runtime.h>

#define EPSBN  1e-5f
#define NBLK_A 392           // 50176 px / 128 per block; 392 = 8*49
#define NBLK_B 392

// ---------------- ws layout (bytes), total 58,861,568 (< proven 61,702,144) ----------------
// w1t2[u][L], u<14, L<12288 : row=L>>6, k = u*64 + (((L>>3&7)^(row&7))<<3)+(L&7); k>=864 -> 0
// w2t [u][L], u<27, L<12288 : same map, k<1728
// wst [t][L], t<2,  L<12288 : same map, k<128 (k>=96 -> 0)
#define W1T_OFF 0u           // 344064
#define W2T_OFF 344064u      // 663552
#define WST_OFF 1007616u     // 49152
#define CS_OFF  1056768u     // 512 f32: [0,192) bias1, [192,384) bias2s, [384,512) zeros
#define XT_OFF  1058816u     // bf16 [64][56][56][96] -> 38535168
#define ACT_OFF 39593984u    // bf16 [64][28][28][192] -> 19267584 (UNPADDED)

#define ZXT   (-256)         // zero scratch as short-index relative to xt  (cs+384 floats)
#define ZACT  (-19267840)    // zero scratch as short-index relative to act

typedef __attribute__((ext_vector_type(8))) short bf16x8;
typedef __attribute__((ext_vector_type(4))) short bf16x4;
typedef __attribute__((ext_vector_type(4))) float f32x4;

__device__ __forceinline__ short f2bf(float f) {
    unsigned u = __float_as_uint(f);
    u += 0x7fffu + ((u >> 16) & 1u);
    return (short)(u >> 16);
}

__device__ __forceinline__ void gload16(const short* g, short* l) {
    __builtin_amdgcn_global_load_lds(
        (const __attribute__((address_space(1))) void*)g,
        (__attribute__((address_space(3))) void*)l, 16, 0, 0);
}

__device__ __forceinline__ float rational_eval(float v, const float* nm, const float* dn) {
    float p = nm[5];
    p = p * v + nm[4];
    p = p * v + nm[3];
    p = p * v + nm[2];
    p = p * v + nm[1];
    p = p * v + nm[0];
    float xa = fabsf(v);
    float q = 1.0f;
    float pw = xa;
    q += dn[0] * pw; pw *= xa;
    q += dn[1] * pw; pw *= xa;
    q += dn[2] * pw; pw *= xa;
    q += dn[3] * pw;
    float inv = __builtin_amdgcn_rcpf(q);
    inv = inv * (2.0f - q * inv);
    return p * inv;
}

__device__ __forceinline__ void sel_coeffs(int v, const float cnm[3][6], const float cdn[3][4],
                                           float nm[6], float dn[4]) {
#pragma unroll
    for (int i = 0; i < 6; i++) nm[i] = (v == 0) ? cnm[0][i] : ((v == 1) ? cnm[1][i] : cnm[2][i]);
#pragma unroll
    for (int i = 0; i < 4; i++) dn[i] = (v == 0) ? cdn[0][i] : ((v == 1) ? cdn[1][i] : cdn[2][i]);
}

// ---------------- fused prep + xpose ----------------
// [0,1296) w2t | [1296,1968) w1t2 | [1968,2064) wst | [2064,5648) xpose | [5648] biases+zeros
extern "C" __global__ __launch_bounds__(256)
void prep_all_kernel(
    const float* __restrict__ x,
    const float* __restrict__ w1, const float* __restrict__ w2, const float* __restrict__ wsc,
    const float* g1, const float* b1, const float* m1, const float* v1,
    const float* g2, const float* b2, const float* m2, const float* v2,
    const float* gs, const float* bs, const float* ms, const float* vs,
    short* __restrict__ w1t, short* __restrict__ w2t, short* __restrict__ wst,
    float* __restrict__ cs, short* __restrict__ xt)
{
    __shared__ float t[96 * 57];
    int blk = blockIdx.x;
    if (blk < 1296) {                               // w2t
        int i = blk * 256 + threadIdx.x;            // < 331776
        int u = i / 12288; int L = i - u * 12288;
        int row = L >> 6; int s = (L >> 3) & 7; int j = L & 7;
        int k = u * 64 + ((s ^ (row & 7)) << 3) + j;
        int kpos = k / 192; int ci = k - kpos * 192;
        float a = g2[row] * rsqrtf(v2[row] + EPSBN);
        w2t[i] = f2bf(w2[(row * 192 + ci) * 9 + kpos] * a);
    } else if (blk < 1968) {                        // w1t2 (K padded 864->896)
        int i = (blk - 1296) * 256 + threadIdx.x;   // < 172032
        int u = i / 12288; int L = i - u * 12288;
        int row = L >> 6; int s = (L >> 3) & 7; int j = L & 7;
        int k = u * 64 + ((s ^ (row & 7)) << 3) + j;
        short val = 0;
        if (k < 864) {
            int kpos = k / 96; int ci = k - kpos * 96;
            float a = g1[row] * rsqrtf(v1[row] + EPSBN);
            val = f2bf(w1[(row * 96 + ci) * 9 + kpos] * a);
        }
        w1t[i] = val;
    } else if (blk < 2064) {                        // wst (K padded to 128)
        int i = (blk - 1968) * 256 + threadIdx.x;   // < 24576
        int u = i / 12288; int L = i - u * 12288;
        int row = L >> 6; int s = (L >> 3) & 7; int j = L & 7;
        int k = u * 64 + ((s ^ (row & 7)) << 3) + j;
        float a = gs[row] * rsqrtf(vs[row] + EPSBN);
        wst[i] = (k < 96) ? f2bf(wsc[row * 96 + k] * a) : (short)0;
    } else if (blk < 5648) {                        // xpose
        int b = blk - 2064;
        int n = b / 56, h = b - n * 56;
        const float* src = x + n * (96 * 3136) + h * 56;
        for (int i = threadIdx.x; i < 96 * 28; i += 256) {
            int c = i / 28, w2i = i - c * 28;
            float2 v = *(const float2*)&src[c * 3136 + w2i * 2];
            t[c * 57 + w2i * 2]     = v.x;
            t[c * 57 + w2i * 2 + 1] = v.y;
        }
        __syncthreads();
        unsigned* dst = (unsigned*)(xt + (n * 56 + h) * 56 * 96);
        for (int i = threadIdx.x; i < 56 * 24; i += 256) {
            int w = i / 24, cp2 = i - (i / 24) * 24;
            unsigned u0 = (unsigned short)f2bf(t[(4 * cp2 + 0) * 57 + w]);
            unsigned u1 = (unsigned short)f2bf(t[(4 * cp2 + 1) * 57 + w]);
            unsigned u2 = (unsigned short)f2bf(t[(4 * cp2 + 2) * 57 + w]);
            unsigned u3 = (unsigned short)f2bf(t[(4 * cp2 + 3) * 57 + w]);
            uint2 pk; pk.x = u0 | (u1 << 16); pk.y = u2 | (u3 << 16);
            *(uint2*)&dst[w * 48 + cp2 * 2] = pk;
        }
    } else {                                        // biases + zero scratch
        int i = threadIdx.x;
        if (i < 192) {
            float a1 = g1[i] * rsqrtf(v1[i] + EPSBN);
            float a2 = g2[i] * rsqrtf(v2[i] + EPSBN);
            float a3 = gs[i] * rsqrtf(vs[i] + EPSBN);
            cs[i]       = b1[i] - m1[i] * a1;
            cs[192 + i] = (b2[i] - m2[i] * a2) + (bs[i] - ms[i] * a3);
        } else if (i < 320) {
            cs[384 + (i - 192)] = 0.f;
        }
    }
}

// ---------------- kernel A: conv1(3x3 s2)+BN1+rational -> act (UNPADDED NHWC bf16) ----------------
// Block 192co x 128px, BK=64 (K padded 896), 2-buffer drain, 80 KB LDS (2 blocks/CU).
extern "C" __global__ __launch_bounds__(512, 4)
void convA_kernel(const short* __restrict__ xt,
                  const short* __restrict__ w1t,
                  const float* __restrict__ bias1,
                  const float* __restrict__ num_r, const float* __restrict__ den_r,
                  const float* __restrict__ num_g, const float* __restrict__ den_g,
                  const float* __restrict__ num_b, const float* __restrict__ den_b,
                  short* __restrict__ act)
{
    __shared__ short lA[2][192 * 64];
    __shared__ short lB[2][128 * 64];

    const int tid  = threadIdx.x;
    const int lane = tid & 63;
    const int wave = tid >> 6;
    const int wm = wave >> 1, wn = wave & 1;
    const int lbid = (blockIdx.x & 7) * 49 + (blockIdx.x >> 3);
    const int p0   = lbid * 128;

    const int s8 = (((tid & 7) ^ ((tid >> 3) & 7))) * 8;   // per-lane k-slot offset (shorts)
    const int rA = tid >> 3;
    const bool c32 = (s8 < 32);

    // per-(pixel-half, tap) adjusted bases: addr = adjvs[c][tap] + t*64 points at xt (or zeros)
    int adjvs[2][10];
#pragma unroll
    for (int c = 0; c < 2; ++c) {
        int p = p0 + c * 64 + rA;
        int n = p / 784; int pr = p - n * 784;
        int oh = pr / 28; int ow = pr - oh * 28;
#pragma unroll
        for (int tap = 0; tap < 9; ++tap) {
            int kh = tap / 3, kw = tap - 3 * kh;
            int ih = 2 * oh + kh - 1, iw = 2 * ow + kw - 1;
            bool valid = (ih >= 0) && (iw >= 0);            // upper bounds always in range
            int base = ((n * 56 + ih) * 56 + iw) * 96;
            adjvs[c][tap] = (valid ? base : ZXT) - 96 * tap + s8;
        }
        adjvs[c][9] = ZXT - 864 + s8;                        // K-pad region (k >= 864)
    }

    const int l15 = lane & 15, ksl = lane >> 4;
    int ard[2][3], brd[2][4];
#pragma unroll
    for (int kk = 0; kk < 2; ++kk) {
#pragma unroll
        for (int m = 0; m < 3; ++m) {
            int row = wm * 48 + m * 16 + l15;
            ard[kk][m] = row * 64 + ((((kk << 2) | ksl) ^ (row & 7)) << 3);
        }
#pragma unroll
        for (int n = 0; n < 4; ++n) {
            int row = wn * 64 + n * 16 + l15;
            brd[kk][n] = row * 64 + ((((kk << 2) | ksl) ^ (row & 7)) << 3);
        }
    }

    const int aoff = wave * 512 + lane * 8;

    f32x4 acc[3][4];
#pragma unroll
    for (int m = 0; m < 3; m++)
#pragma unroll
        for (int n = 0; n < 4; n++) acc[m][n] = (f32x4){0.f, 0.f, 0.f, 0.f};

    // per-step tap tables (straddle steps: t % 3 == 1, lane split at s8 < 32)
    const int LO[14] = {0,0,1,2,2,3,4,4,5,6,6,7,8,8};
    const int HI[14] = {0,1,1,2,3,3,4,5,5,6,7,7,8,9};

#define STAGE_A(buf, t_)                                                                    \
    do {                                                                                    \
        const int t__ = (t_);                                                               \
        const short* aw = &w1t[t__ * 12288 + aoff];                                         \
        _Pragma("unroll") for (int c3 = 0; c3 < 3; ++c3)                                    \
            gload16(aw + c3 * 4096, &lA[buf][c3 * 4096 + wave * 512]);                      \
        _Pragma("unroll") for (int c = 0; c < 2; ++c) {                                     \
            int av = (LO[t__] == HI[t__]) ? adjvs[c][LO[t__]]                               \
                     : (c32 ? adjvs[c][LO[t__]] : adjvs[c][HI[t__]]);                       \
            gload16(&xt[av + t__ * 64], &lB[buf][c * 4096 + wave * 512]);                   \
        }                                                                                   \
    } while (0)

    STAGE_A(0, 0);
#pragma unroll
    for (int t = 0; t < 14; ++t) {
        const int cur = t & 1;
        __syncthreads();
        if (t + 1 < 14) STAGE_A(cur ^ 1, t + 1);
        __builtin_amdgcn_s_setprio(1);
#pragma unroll
        for (int kk = 0; kk < 2; ++kk) {
            bf16x8 af[3];
#pragma unroll
            for (int m = 0; m < 3; ++m) af[m] = *(const bf16x8*)&lA[cur][ard[kk][m]];
#pragma unroll
            for (int n = 0; n < 4; ++n) {
                bf16x8 bv = *(const bf16x8*)&lB[cur][brd[kk][n]];
#pragma unroll
                for (int m = 0; m < 3; ++m)
                    acc[m][n] = __builtin_amdgcn_mfma_f32_16x16x32_bf16(af[m], bv, acc[m][n], 0, 0, 0);
            }
        }
        __builtin_amdgcn_s_setprio(0);
    }
#undef STAGE_A

    // epilogue: bias + rational -> act (UNPADDED NHWC, packed short4)
    float cnm[3][6], cdn[3][4];
#pragma unroll
    for (int i = 0; i < 6; i++) { cnm[0][i] = num_r[i]; cnm[1][i] = num_g[i]; cnm[2][i] = num_b[i]; }
#pragma unroll
    for (int i = 0; i < 4; i++) { cdn[0][i] = fabsf(den_r[i]); cdn[1][i] = fabsf(den_g[i]); cdn[2][i] = fabsf(den_b[i]); }

    int abase[4];
#pragma unroll
    for (int n = 0; n < 4; ++n) {
        int pp = p0 + wn * 64 + n * 16 + l15;
        int n2 = pp / 784; int r2 = pp - n2 * 784;
        int oh2 = r2 / 28; int ow2 = r2 - oh2 * 28;
        abase[n] = ((n2 * 28 + oh2) * 28 + ow2) * 192;
    }
#pragma unroll
    for (int m = 0; m < 3; ++m) {
        int cob = wm * 48 + m * 16 + (ksl << 2);
        float res[4][4];
#pragma unroll
        for (int r = 0; r < 4; ++r) {
            float nm[6], dn[4];
            sel_coeffs((cob + r) % 3, cnm, cdn, nm, dn);
            float bv = bias1[cob + r];
#pragma unroll
            for (int n = 0; n < 4; ++n)
                res[n][r] = rational_eval(acc[m][n][r] + bv, nm, dn);
        }
#pragma unroll
        for (int n = 0; n < 4; ++n) {
            bf16x4 pk;
#pragma unroll
            for (int r = 0; r < 4; ++r) pk[r] = f2bf(res[n][r]);
            *(bf16x4*)&act[abase[n] + cob] = pk;
        }
    }
}

// ---------------- kernel B: shortcut(1x1 s2, K=128 padded) + conv2(3x3 s1, K=1728) into one acc;
// fused bias + rational -> out (NCHW f32). Block 192co x 128px, BK=64, UNPADDED act
// with per-tap validity bases. Fully unrolled. ----------------
extern "C" __global__ __launch_bounds__(512, 4)
void convB_kernel(const short* __restrict__ act,
                  const short* __restrict__ xt,
                  const short* __restrict__ w2t,
                  const short* __restrict__ wst,
                  const float* __restrict__ bias2s,
                  const float* __restrict__ num_r, const float* __restrict__ den_r,
                  const float* __restrict__ num_g, const float* __restrict__ den_g,
                  const float* __restrict__ num_b, const float* __restrict__ den_b,
                  float* __restrict__ outp)
{
    __shared__ short lA[2][192 * 64];
    __shared__ short lB[2][128 * 64];

    const int tid  = threadIdx.x;
    const int lane = tid & 63;
    const int wave = tid >> 6;
    const int wm = wave >> 1, wn = wave & 1;
    const int lbid = (blockIdx.x & 7) * 49 + (blockIdx.x >> 3);
    const int p0   = lbid * 128;

    const int s8 = (((tid & 7) ^ ((tid >> 3) & 7))) * 8;
    const int rA = tid >> 3;

    // per-(pixel-half, tap) act bases (+validity); addr = adjB[c][tap] + cb*64
    int adjB[2][9], xcB[2];
#pragma unroll
    for (int c = 0; c < 2; ++c) {
        int p = p0 + c * 64 + rA;
        int n = p / 784; int pr = p - n * 784;
        int oh = pr / 28; int ow = pr - oh * 28;
        xcB[c] = ((n * 56 + 2 * oh) * 56 + 2 * ow) * 96 + s8;
#pragma unroll
        for (int tap = 0; tap < 9; ++tap) {
            int kh = tap / 3, kw = tap - 3 * kh;
            int ih = oh + kh - 1, iw = ow + kw - 1;
            bool valid = (ih >= 0) && (ih < 28) && (iw >= 0) && (iw < 28);
            int base = ((n * 28 + ih) * 28 + iw) * 192;
            adjB[c][tap] = (valid ? base : ZACT) + s8;
        }
    }

    const int l15 = lane & 15, ksl = lane >> 4;
    int ard[2][3], brd[2][4];
#pragma unroll
    for (int kk = 0; kk < 2; ++kk) {
#pragma unroll
        for (int m = 0; m < 3; ++m) {
            int row = wm * 48 + m * 16 + l15;
            ard[kk][m] = row * 64 + ((((kk << 2) | ksl) ^ (row & 7)) << 3);
        }
#pragma unroll
        for (int n = 0; n < 4; ++n) {
            int row = wn * 64 + n * 16 + l15;
            brd[kk][n] = row * 64 + ((((kk << 2) | ksl) ^ (row & 7)) << 3);
        }
    }

    const int aoff = wave * 512 + lane * 8;

#define STAGE_B(buf, t_)                                                                    \
    do {                                                                                    \
        const int t__ = (t_);                                                               \
        if (t__ < 2) {                                                                      \
            const short* aw = &wst[t__ * 12288 + aoff];                                     \
            _Pragma("unroll") for (int c3 = 0; c3 < 3; ++c3)                                \
                gload16(aw + c3 * 4096, &lA[buf][c3 * 4096 + wave * 512]);                  \
            _Pragma("unroll") for (int c = 0; c < 2; ++c)                                   \
                gload16(&xt[xcB[c] + t__ * 64], &lB[buf][c * 4096 + wave * 512]);           \
        } else {                                                                            \
            const int u__ = t__ - 2;                                                        \
            const int tap__ = u__ / 3, cb__ = u__ - 3 * tap__;                              \
            const short* aw = &w2t[u__ * 12288 + aoff];                                     \
            _Pragma("unroll") for (int c3 = 0; c3 < 3; ++c3)                                \
                gload16(aw + c3 * 4096, &lA[buf][c3 * 4096 + wave * 512]);                  \
            _Pragma("unroll") for (int c = 0; c < 2; ++c)                                   \
                gload16(&act[adjB[c][tap__] + cb__ * 64], &lB[buf][c * 4096 + wave * 512]); \
        }                                                                                   \
    } while (0)

    f32x4 acc[3][4];
#pragma unroll
    for (int m = 0; m < 3; m++)
#pragma unroll
        for (int n = 0; n < 4; n++) acc[m][n] = (f32x4){0.f, 0.f, 0.f, 0.f};

    STAGE_B(0, 0);
#pragma unroll
    for (int t = 0; t < 29; ++t) {
        const int cur = t & 1;
        __syncthreads();
        if (t + 1 < 29) STAGE_B(cur ^ 1, t + 1);
        __builtin_amdgcn_s_setprio(1);
#pragma unroll
        for (int kk = 0; kk < 2; ++kk) {
            bf16x8 af[3];
#pragma unroll
            for (int m = 0; m < 3; ++m) af[m] = *(const bf16x8*)&lA[cur][ard[kk][m]];
#pragma unroll
            for (int n = 0; n < 4; ++n) {
                bf16x8 bv = *(const bf16x8*)&lB[cur][brd[kk][n]];
#pragma unroll
                for (int m = 0; m < 3; ++m)
                    acc[m][n] = __builtin_amdgcn_mfma_f32_16x16x32_bf16(af[m], bv, acc[m][n], 0, 0, 0);
            }
        }
        __builtin_amdgcn_s_setprio(0);
    }
#undef STAGE_B

    float cnm[3][6], cdn[3][4];
#pragma unroll
    for (int i = 0; i < 6; i++) { cnm[0][i] = num_r[i]; cnm[1][i] = num_g[i]; cnm[2][i] = num_b[i]; }
#pragma unroll
    for (int i = 0; i < 4; i++) { cdn[0][i] = fabsf(den_r[i]); cdn[1][i] = fabsf(den_g[i]); cdn[2][i] = fabsf(den_b[i]); }

    int obase[4];
#pragma unroll
    for (int n = 0; n < 4; ++n) {
        int pp = p0 + wn * 64 + n * 16 + l15;
        int n2 = pp / 784; int r2 = pp - n2 * 784;
        int oh2 = r2 / 28; int ow2 = r2 - oh2 * 28;
        obase[n] = n2 * (192 * 784) + oh2 * 28 + ow2;
    }
#pragma unroll
    for (int m = 0; m < 3; ++m) {
        int cob = wm * 48 + m * 16 + (ksl << 2);
#pragma unroll
        for (int r = 0; r < 4; ++r) {
            float nm[6], dn[4];
            sel_coeffs((cob + r) % 3, cnm, cdn, nm, dn);
            float bv = bias2s[cob + r];
#pragma unroll
            for (int n = 0; n < 4; ++n) {
                int idx = obase[n] + (cob + r) * 784;
                outp[idx] = rational_eval(acc[m][n][r] + bv, nm, dn);
            }
        }
    }
}

// ---------------- launcher ----------------
extern "C" void kernel_launch(void* const* d_in, const int* in_sizes, int n_in,
                              void* d_out, int out_size, void* d_ws, size_t ws_size,
                              hipStream_t stream)
{
    const float* x      = (const float*)d_in[0];
    const float* w1     = (const float*)d_in[1];
    const float* gamma1 = (const float*)d_in[2];
    const float* beta1  = (const float*)d_in[3];
    const float* mean1  = (const float*)d_in[4];
    const float* var1   = (const float*)d_in[5];
    const float* num_r  = (const float*)d_in[6];
    const float* den_r  = (const float*)d_in[7];
    const float* num_g  = (const float*)d_in[8];
    const float* den_g  = (const float*)d_in[9];
    const float* num_b  = (const float*)d_in[10];
    const float* den_b  = (const float*)d_in[11];
    const float* w2     = (const float*)d_in[12];
    const float* gamma2 = (const float*)d_in[13];
    const float* beta2  = (const float*)d_in[14];
    const float* mean2  = (const float*)d_in[15];
    const float* var2   = (const float*)d_in[16];
    const float* wsc    = (const float*)d_in[17];
    const float* gammas = (const float*)d_in[18];
    const float* betas  = (const float*)d_in[19];
    const float* means  = (const float*)d_in[20];
    const float* vars_  = (const float*)d_in[21];

    char* base = (char*)d_ws;
    short* w1t  = (short*)(base + W1T_OFF);
    short* w2t  = (short*)(base + W2T_OFF);
    short* wst  = (short*)(base + WST_OFF);
    float* cs   = (float*)(base + CS_OFF);
    short* xt   = (short*)(base + XT_OFF);
    short* act  = (short*)(base + ACT_OFF);
    float* outp = (float*)d_out;

    float* bias1  = cs;
    float* bias2s = cs + 192;

    prep_all_kernel<<<5649, 256, 0, stream>>>(x, w1, w2, wsc,
                                              gamma1, beta1, mean1, var1,
                                              gamma2, beta2, mean2, var2,
                                              gammas, betas, means, vars_,
                                              w1t, w2t, wst, cs, xt);

    convA_kernel<<<NBLK_A, 512, 0, stream>>>(xt, w1t, bias1,
                                             num_r, den_r, num_g, den_g, num_b, den_b,
                                             act);

    convB_kernel<<<NBLK_B, 512, 0, stream>>>(act, xt, w2t, wst, bias2s,
                                             num_r, den_r, num_g, den_g, num_b, den_b,
                                             outp);
}